// Round 1
// baseline (247.868 us; speedup 1.0000x reference)
//
#include <hip/hip_runtime.h>

#define Bq 32
#define Aq 8400
#define Cq 80
#define Mq 32
#define TOPK 13
#define EPSq 1e-9f

// iou = inter / (area_g + area_p - inter + EPS), matching reference op order
__device__ __forceinline__ float iou_calc(float gx1, float gy1, float gx2, float gy2,
                                          float px1, float py1, float px2, float py2,
                                          float garea) {
    float ix1 = fmaxf(gx1, px1), iy1 = fmaxf(gy1, py1);
    float ix2 = fminf(gx2, px2), iy2 = fminf(gy2, py2);
    float iw = fmaxf(ix2 - ix1, 0.f), ih = fmaxf(iy2 - iy1, 0.f);
    float inter = iw * ih;
    float parea = (px2 - px1) * (py2 - py1);
    return inter / (((garea + parea) - inter) + EPSq);
}

__device__ __forceinline__ float in_gts_min(float ax, float ay,
                                            float gx1, float gy1, float gx2, float gy2) {
    return fminf(fminf(ax - gx1, ay - gy1), fminf(gx2 - ax, gy2 - ay));
}

// K1: per (b,m) top-13 of align_metric over anchors; set bit m in posmask for
// selected anchors that are inside the gt box.
__global__ __launch_bounds__(256) void k_topk(
    const float* __restrict__ pd_scores, const float* __restrict__ pd_bboxes,
    const float* __restrict__ anc, const int* __restrict__ gt_labels,
    const float* __restrict__ gt_bboxes, const float* __restrict__ mask_gt,
    unsigned int* __restrict__ posmask)
{
    int m = blockIdx.x, b = blockIdx.y;
    float mg = mask_gt[b * Mq + m];
    if (mg <= 0.f) return;  // masked gt: reference scatters all 13 picks to idx 0 -> counts>1 -> no positives

    __shared__ float vals[Aq];
    __shared__ float rv[256];
    __shared__ int   ri[256];
    __shared__ int   winner[TOPK];

    int t = threadIdx.x;
    int lbl = gt_labels[b * Mq + m];
    const float* gb = gt_bboxes + (b * Mq + m) * 4;
    float gx1 = gb[0], gy1 = gb[1], gx2 = gb[2], gy2 = gb[3];
    float garea = (gx2 - gx1) * (gy2 - gy1);

    for (int a = t; a < Aq; a += 256) {
        float ax = anc[2 * a], ay = anc[2 * a + 1];
        float al = 0.f;
        if (in_gts_min(ax, ay, gx1, gy1, gx2, gy2) > EPSq) {
            const float* pb = pd_bboxes + ((size_t)b * Aq + a) * 4;
            float iou = iou_calc(gx1, gy1, gx2, gy2, pb[0], pb[1], pb[2], pb[3], garea);
            float ov = fmaxf(iou, 0.f);
            float sc = pd_scores[(size_t)b * Aq * Cq + (size_t)a * Cq + lbl];
            float o2 = ov * ov;
            al = sc * (o2 * o2 * o2);
        }
        vals[a] = al;
    }
    __syncthreads();

    // 13 rounds of block argmax, tie -> lowest index (lax.top_k stable order)
    for (int k = 0; k < TOPK; k++) {
        float bv = -1.f; int bi = 0;
        for (int a = t; a < Aq; a += 256) {
            float v = vals[a];
            if (v > bv) { bv = v; bi = a; }  // strict > keeps lowest index within thread
        }
        rv[t] = bv; ri[t] = bi;
        __syncthreads();
        for (int s = 128; s > 0; s >>= 1) {
            if (t < s) {
                float v2 = rv[t + s]; int i2 = ri[t + s];
                if (v2 > rv[t] || (v2 == rv[t] && i2 < ri[t])) { rv[t] = v2; ri[t] = i2; }
            }
            __syncthreads();
        }
        if (t == 0) { winner[k] = ri[0]; vals[ri[0]] = -1.f; }
        __syncthreads();
    }

    if (t < TOPK) {
        int a = winner[t];
        float ax = anc[2 * a], ay = anc[2 * a + 1];
        if (in_gts_min(ax, ay, gx1, gy1, gx2, gy2) > EPSq) {
            atomicOr(&posmask[b * Aq + a], 1u << m);
        }
    }
}

// K2: resolve multi-gt anchors via argmax(overlaps over all m); write final mask,
// tgt_bboxes, fg; accumulate pos_am / pos_ov per gt via float-bits atomicMax.
__global__ __launch_bounds__(256) void k_resolve(
    const float* __restrict__ pd_scores, const float* __restrict__ pd_bboxes,
    const float* __restrict__ anc, const int* __restrict__ gt_labels,
    const float* __restrict__ gt_bboxes, const float* __restrict__ mask_gt,
    const unsigned int* __restrict__ posmask,
    unsigned int* __restrict__ finalmask,
    float* __restrict__ asel,
    unsigned int* __restrict__ pos_am, unsigned int* __restrict__ pos_ov,
    float* __restrict__ out_bboxes, float* __restrict__ out_fg)
{
    int a = blockIdx.x * 256 + threadIdx.x;
    int b = blockIdx.y;
    if (a >= Aq) return;

    unsigned int w = posmask[b * Aq + a];
    const float* pb = pd_bboxes + ((size_t)b * Aq + a) * 4;
    float px1 = pb[0], py1 = pb[1], px2 = pb[2], py2 = pb[3];
    float ax = anc[2 * a], ay = anc[2 * a + 1];

    if (__popc(w) > 1) {
        // reference: argmax over ALL m of masked overlaps, first-max wins (m=0 if all zero)
        float bv = -1.f; int bj = 0;
        for (int mm = 0; mm < Mq; mm++) {
            const float* gb = gt_bboxes + (b * Mq + mm) * 4;
            float gx1 = gb[0], gy1 = gb[1], gx2 = gb[2], gy2 = gb[3];
            float ov = 0.f;
            if (in_gts_min(ax, ay, gx1, gy1, gx2, gy2) > EPSq && mask_gt[b * Mq + mm] > 0.f) {
                float garea = (gx2 - gx1) * (gy2 - gy1);
                ov = fmaxf(iou_calc(gx1, gy1, gx2, gy2, px1, py1, px2, py2, garea), 0.f);
            }
            if (ov > bv) { bv = ov; bj = mm; }
        }
        w = 1u << bj;
    }
    finalmask[b * Aq + a] = w;

    int j = w ? (__ffs(w) - 1) : 0;  // argmax of mask_pos: first set bit, else 0
    const float* gbj = gt_bboxes + (b * Mq + j) * 4;
    float gx1 = gbj[0], gy1 = gbj[1], gx2 = gbj[2], gy2 = gbj[3];

    float4 tb = make_float4(gx1, gy1, gx2, gy2);
    ((float4*)out_bboxes)[(size_t)b * Aq + a] = tb;
    out_fg[b * Aq + a] = w ? 1.f : 0.f;

    if (w) {
        float al = 0.f, ov = 0.f;
        if (in_gts_min(ax, ay, gx1, gy1, gx2, gy2) > EPSq && mask_gt[b * Mq + j] > 0.f) {
            float garea = (gx2 - gx1) * (gy2 - gy1);
            ov = fmaxf(iou_calc(gx1, gy1, gx2, gy2, px1, py1, px2, py2, garea), 0.f);
            float sc = pd_scores[(size_t)b * Aq * Cq + (size_t)a * Cq + gt_labels[b * Mq + j]];
            float o2 = ov * ov;
            al = sc * (o2 * o2 * o2);
        }
        asel[b * Aq + a] = al;
        atomicMax(&pos_am[b * Mq + j], __float_as_uint(al));
        atomicMax(&pos_ov[b * Mq + j], __float_as_uint(ov));
    }
}

// K3: per-anchor norm + target label
__global__ __launch_bounds__(256) void k_norm(
    const int* __restrict__ gt_labels,
    const unsigned int* __restrict__ finalmask,
    const float* __restrict__ asel,
    const unsigned int* __restrict__ pos_am, const unsigned int* __restrict__ pos_ov,
    float* __restrict__ normv, int* __restrict__ tlab)
{
    int a = blockIdx.x * 256 + threadIdx.x;
    int b = blockIdx.y;
    if (a >= Aq) return;
    unsigned int w = finalmask[b * Aq + a];
    float nv = 0.f; int lb = 0;
    if (w) {
        int j = __ffs(w) - 1;
        lb = gt_labels[b * Mq + j];
        float pam = __uint_as_float(pos_am[b * Mq + j]);
        float pov = __uint_as_float(pos_ov[b * Mq + j]);
        nv = asel[b * Aq + a] * pov / (pam + EPSq);
    }
    normv[b * Aq + a] = nv;
    tlab[b * Aq + a] = lb;
}

// K4: target_scores = one_hot(label) * norm  (norm already 0 where fg==0)
__global__ __launch_bounds__(256) void k_scores(
    const float* __restrict__ normv, const int* __restrict__ tlab,
    float* __restrict__ out_scores)
{
    int i = blockIdx.x * 256 + threadIdx.x;
    if (i >= Bq * Aq * Cq) return;
    int c = i % Cq;
    int ba = i / Cq;
    float nv = normv[ba];
    int lb = tlab[ba];
    out_scores[i] = (c == lb) ? nv : 0.f;
}

extern "C" void kernel_launch(void* const* d_in, const int* in_sizes, int n_in,
                              void* d_out, int out_size, void* d_ws, size_t ws_size,
                              hipStream_t stream) {
    const float* pd_scores = (const float*)d_in[0];
    const float* pd_bboxes = (const float*)d_in[1];
    const float* anc       = (const float*)d_in[2];
    const int*   gt_labels = (const int*)d_in[3];
    const float* gt_bboxes = (const float*)d_in[4];
    const float* mask_gt   = (const float*)d_in[5];

    float* out_bboxes = (float*)d_out;                          // B*A*4
    float* out_scores = out_bboxes + (size_t)Bq * Aq * 4;       // B*A*C
    float* out_fg     = out_scores + (size_t)Bq * Aq * Cq;      // B*A

    char* ws = (char*)d_ws;
    const size_t BA4 = (size_t)Bq * Aq * 4;                     // bytes per B*A word array
    unsigned int* posmask   = (unsigned int*)ws;  ws += BA4;
    unsigned int* finalmask = (unsigned int*)ws;  ws += BA4;
    float*        asel      = (float*)ws;         ws += BA4;
    float*        normv     = (float*)ws;         ws += BA4;
    int*          tlab      = (int*)ws;           ws += BA4;
    unsigned int* pos_am    = (unsigned int*)ws;  ws += (size_t)Bq * Mq * 4;
    unsigned int* pos_ov    = (unsigned int*)ws;  ws += (size_t)Bq * Mq * 4;

    hipMemsetAsync(posmask, 0, BA4, stream);
    hipMemsetAsync(pos_am, 0, (size_t)Bq * Mq * 4, stream);
    hipMemsetAsync(pos_ov, 0, (size_t)Bq * Mq * 4, stream);

    k_topk<<<dim3(Mq, Bq), 256, 0, stream>>>(
        pd_scores, pd_bboxes, anc, gt_labels, gt_bboxes, mask_gt, posmask);

    k_resolve<<<dim3((Aq + 255) / 256, Bq), 256, 0, stream>>>(
        pd_scores, pd_bboxes, anc, gt_labels, gt_bboxes, mask_gt,
        posmask, finalmask, asel, pos_am, pos_ov, out_bboxes, out_fg);

    k_norm<<<dim3((Aq + 255) / 256, Bq), 256, 0, stream>>>(
        gt_labels, finalmask, asel, pos_am, pos_ov, normv, tlab);

    k_scores<<<(Bq * Aq * Cq + 255) / 256, 256, 0, stream>>>(normv, tlab, out_scores);
}

// Round 2
// 223.347 us; speedup vs baseline: 1.1098x; 1.1098x over previous
//
#include <hip/hip_runtime.h>

#define Bq 32
#define Aq 8400
#define Cq 80
#define Mq 32
#define TOPK 13
#define EPSq 1e-9f

// total order: value desc, index asc — matches lax.top_k stable ordering
__device__ __forceinline__ bool better(float v1, int i1, float v2, int i2) {
    return (v1 > v2) || ((v1 == v2) && (i1 < i2));
}

__device__ __forceinline__ float iou4(float4 g, float4 p, float garea) {
    float ix1 = fmaxf(g.x, p.x), iy1 = fmaxf(g.y, p.y);
    float ix2 = fminf(g.z, p.z), iy2 = fminf(g.w, p.w);
    float iw = fmaxf(ix2 - ix1, 0.f), ih = fmaxf(iy2 - iy1, 0.f);
    float inter = iw * ih;
    float parea = (p.z - p.x) * (p.w - p.y);
    return inter / (((garea + parea) - inter) + EPSq);
}

__device__ __forceinline__ float in_min4(float ax, float ay, float4 g) {
    return fminf(fminf(ax - g.x, ay - g.y), fminf(g.z - ax, g.w - ay));
}

// K1: per (b,m) top-13 of align_metric via streaming register top-K + wave merges.
__global__ __launch_bounds__(256) void k_topk(
    const float* __restrict__ pd_scores, const float* __restrict__ pd_bboxes,
    const float* __restrict__ anc, const int* __restrict__ gt_labels,
    const float* __restrict__ gt_bboxes, const float* __restrict__ mask_gt,
    unsigned int* __restrict__ posmask)
{
    int m = blockIdx.x, b = blockIdx.y;
    if (mask_gt[b * Mq + m] <= 0.f) return;  // masked gt: reference yields no positives

    __shared__ float sv[4 * 16];
    __shared__ int   si[4 * 16];

    int tid = threadIdx.x;
    int lane = tid & 63, w = tid >> 6;

    int lbl = gt_labels[b * Mq + m];
    float4 gb = ((const float4*)gt_bboxes)[b * Mq + m];
    float garea = (gb.z - gb.x) * (gb.w - gb.y);

    float val[TOPK]; int idx[TOPK];
    #pragma unroll
    for (int k = 0; k < TOPK; k++) { val[k] = -1.f; idx[k] = 0x7fffffff; }

    for (int a = tid; a < Aq; a += 256) {
        float2 ap = ((const float2*)anc)[a];
        float al = 0.f;
        if (in_min4(ap.x, ap.y, gb) > EPSq) {
            float4 pb = ((const float4*)pd_bboxes)[(size_t)b * Aq + a];
            float ov = fmaxf(iou4(gb, pb, garea), 0.f);
            float sc = pd_scores[((size_t)b * Aq + a) * Cq + lbl];
            float o2 = ov * ov;
            al = sc * (o2 * o2 * o2);
        }
        // branch-free sorted insert (fast-path skip when worse than tail)
        if (better(al, a, val[TOPK - 1], idx[TOPK - 1])) {
            #pragma unroll
            for (int k = TOPK - 1; k >= 1; --k) {
                bool bk   = better(val[k],     idx[k],     al, a);
                bool bkm1 = better(val[k - 1], idx[k - 1], al, a);
                val[k] = bk ? val[k] : (bkm1 ? al : val[k - 1]);
                idx[k] = bk ? idx[k] : (bkm1 ? a  : idx[k - 1]);
            }
            bool b0 = better(val[0], idx[0], al, a);
            val[0] = b0 ? val[0] : al;
            idx[0] = b0 ? idx[0] : a;
        }
    }

    // wave-level: 13 rounds of butterfly argmax over per-lane heads, pop winner
    float rec_v = -1.f; int rec_i = 0x7fffffff;
    #pragma unroll
    for (int r = 0; r < TOPK; ++r) {
        float bv = val[0]; int bi = idx[0];
        #pragma unroll
        for (int off = 1; off < 64; off <<= 1) {
            float ovv = __shfl_xor(bv, off);
            int   oii = __shfl_xor(bi, off);
            if (better(ovv, oii, bv, bi)) { bv = ovv; bi = oii; }
        }
        if (lane == r) { rec_v = bv; rec_i = bi; }
        if (idx[0] == bi) {  // unique winner: pop my head
            #pragma unroll
            for (int k = 0; k < TOPK - 1; ++k) { val[k] = val[k + 1]; idx[k] = idx[k + 1]; }
            val[TOPK - 1] = -1.f; idx[TOPK - 1] = 0x7fffffff;
        }
    }
    if (lane < TOPK) { sv[w * 16 + lane] = rec_v; si[w * 16 + lane] = rec_i; }
    __syncthreads();

    // wave 0: merge 4x13 candidates (all real, all distinct anchors)
    if (w == 0) {
        float cv = -1.f; int ci = 0x7fffffff;
        if (lane < 4 * TOPK) {
            int ww = lane / TOPK, rr = lane - ww * TOPK;
            cv = sv[ww * 16 + rr]; ci = si[ww * 16 + rr];
        }
        int   win_i = 0x7fffffff;
        #pragma unroll
        for (int r = 0; r < TOPK; ++r) {
            float bv = cv; int bi = ci;
            #pragma unroll
            for (int off = 1; off < 64; off <<= 1) {
                float ovv = __shfl_xor(bv, off);
                int   oii = __shfl_xor(bi, off);
                if (better(ovv, oii, bv, bi)) { bv = ovv; bi = oii; }
            }
            if (lane == r) { win_i = bi; }
            if (ci == bi) { cv = -1.f; ci = 0x7fffffff; }  // pop
        }
        if (lane < TOPK) {
            int a = win_i;
            float2 ap = ((const float2*)anc)[a];
            if (in_min4(ap.x, ap.y, gb) > EPSq) {  // mask_in_gts applies after top-k
                atomicOr(&posmask[b * Aq + a], 1u << m);
            }
        }
    }
}

// K2: resolve multi-gt anchors via argmax(overlaps over all m); write final mask,
// tgt_bboxes, fg; accumulate pos_am / pos_ov per gt via float-bits atomicMax.
__global__ __launch_bounds__(256) void k_resolve(
    const float* __restrict__ pd_scores, const float* __restrict__ pd_bboxes,
    const float* __restrict__ anc, const int* __restrict__ gt_labels,
    const float* __restrict__ gt_bboxes, const float* __restrict__ mask_gt,
    const unsigned int* __restrict__ posmask,
    unsigned int* __restrict__ finalmask,
    float* __restrict__ asel,
    unsigned int* __restrict__ pos_am, unsigned int* __restrict__ pos_ov,
    float* __restrict__ out_bboxes, float* __restrict__ out_fg)
{
    int a = blockIdx.x * 256 + threadIdx.x;
    int b = blockIdx.y;
    if (a >= Aq) return;

    unsigned int w = posmask[b * Aq + a];
    float4 pb = ((const float4*)pd_bboxes)[(size_t)b * Aq + a];
    float2 ap = ((const float2*)anc)[a];

    if (__popc(w) > 1) {
        // reference: argmax over ALL m of masked overlaps, first-max wins
        float bv = -1.f; int bj = 0;
        for (int mm = 0; mm < Mq; mm++) {
            float4 g = ((const float4*)gt_bboxes)[b * Mq + mm];
            float ov = 0.f;
            if (in_min4(ap.x, ap.y, g) > EPSq && mask_gt[b * Mq + mm] > 0.f) {
                float garea = (g.z - g.x) * (g.w - g.y);
                ov = fmaxf(iou4(g, pb, garea), 0.f);
            }
            if (ov > bv) { bv = ov; bj = mm; }
        }
        w = 1u << bj;
    }
    finalmask[b * Aq + a] = w;

    int j = w ? (__ffs(w) - 1) : 0;  // argmax of mask_pos: first set bit, else 0
    float4 g = ((const float4*)gt_bboxes)[b * Mq + j];
    ((float4*)out_bboxes)[(size_t)b * Aq + a] = g;
    out_fg[b * Aq + a] = w ? 1.f : 0.f;

    if (w) {
        float al = 0.f, ov = 0.f;
        if (in_min4(ap.x, ap.y, g) > EPSq && mask_gt[b * Mq + j] > 0.f) {
            float garea = (g.z - g.x) * (g.w - g.y);
            ov = fmaxf(iou4(g, pb, garea), 0.f);
            float sc = pd_scores[((size_t)b * Aq + a) * Cq + gt_labels[b * Mq + j]];
            float o2 = ov * ov;
            al = sc * (o2 * o2 * o2);
        }
        asel[b * Aq + a] = al;
        atomicMax(&pos_am[b * Mq + j], __float_as_uint(al));
        atomicMax(&pos_ov[b * Mq + j], __float_as_uint(ov));
    }
}

// K3 (fused norm+scores): target_scores = one_hot(label) * norm, float4 stores.
__global__ __launch_bounds__(256) void k_scores(
    const int* __restrict__ gt_labels,
    const unsigned int* __restrict__ finalmask,
    const float* __restrict__ asel,
    const unsigned int* __restrict__ pos_am, const unsigned int* __restrict__ pos_ov,
    float* __restrict__ out_scores)
{
    int i4 = blockIdx.x * 256 + threadIdx.x;
    if (i4 >= Bq * Aq * Cq / 4) return;
    int i = i4 * 4;
    int c0 = i % Cq;          // Cq % 4 == 0, so all 4 lanes share one ba
    int ba = i / Cq;
    unsigned int w = finalmask[ba];
    float4 o = make_float4(0.f, 0.f, 0.f, 0.f);
    if (w) {
        int b = ba / Aq;
        int j = __ffs(w) - 1;
        int lb = gt_labels[b * Mq + j];
        if (lb >= c0 && lb < c0 + 4) {
            float pam = __uint_as_float(pos_am[b * Mq + j]);
            float pov = __uint_as_float(pos_ov[b * Mq + j]);
            float nv = asel[ba] * pov / (pam + EPSq);
            o.x = (lb == c0    ) ? nv : 0.f;
            o.y = (lb == c0 + 1) ? nv : 0.f;
            o.z = (lb == c0 + 2) ? nv : 0.f;
            o.w = (lb == c0 + 3) ? nv : 0.f;
        }
    }
    ((float4*)out_scores)[i4] = o;
}

extern "C" void kernel_launch(void* const* d_in, const int* in_sizes, int n_in,
                              void* d_out, int out_size, void* d_ws, size_t ws_size,
                              hipStream_t stream) {
    const float* pd_scores = (const float*)d_in[0];
    const float* pd_bboxes = (const float*)d_in[1];
    const float* anc       = (const float*)d_in[2];
    const int*   gt_labels = (const int*)d_in[3];
    const float* gt_bboxes = (const float*)d_in[4];
    const float* mask_gt   = (const float*)d_in[5];

    float* out_bboxes = (float*)d_out;                          // B*A*4
    float* out_scores = out_bboxes + (size_t)Bq * Aq * 4;       // B*A*C
    float* out_fg     = out_scores + (size_t)Bq * Aq * Cq;      // B*A

    char* ws = (char*)d_ws;
    const size_t BA4 = (size_t)Bq * Aq * 4;                     // bytes per B*A word array
    unsigned int* posmask   = (unsigned int*)ws;  ws += BA4;
    unsigned int* finalmask = (unsigned int*)ws;  ws += BA4;
    float*        asel      = (float*)ws;         ws += BA4;
    unsigned int* pos_am    = (unsigned int*)ws;  ws += (size_t)Bq * Mq * 4;
    unsigned int* pos_ov    = (unsigned int*)ws;  ws += (size_t)Bq * Mq * 4;

    hipMemsetAsync(posmask, 0, BA4, stream);
    hipMemsetAsync(pos_am, 0, (size_t)Bq * Mq * 4, stream);
    hipMemsetAsync(pos_ov, 0, (size_t)Bq * Mq * 4, stream);

    k_topk<<<dim3(Mq, Bq), 256, 0, stream>>>(
        pd_scores, pd_bboxes, anc, gt_labels, gt_bboxes, mask_gt, posmask);

    k_resolve<<<dim3((Aq + 255) / 256, Bq), 256, 0, stream>>>(
        pd_scores, pd_bboxes, anc, gt_labels, gt_bboxes, mask_gt,
        posmask, finalmask, asel, pos_am, pos_ov, out_bboxes, out_fg);

    k_scores<<<(Bq * Aq * Cq / 4 + 255) / 256, 256, 0, stream>>>(
        gt_labels, finalmask, asel, pos_am, pos_ov, out_scores);
}